// Round 11
// baseline (906.042 us; speedup 1.0000x reference)
//
#include <hip/hip_runtime.h>

typedef unsigned short u16;
typedef __attribute__((ext_vector_type(8))) short bf16x8;
typedef __attribute__((ext_vector_type(4))) float f32x4;
typedef __attribute__((ext_vector_type(4))) int   i32x4;

#define DEVFN static __device__ __forceinline__
#define AS_G __attribute__((address_space(1)))
#define AS_L __attribute__((address_space(3)))

DEVFN float b2f(u16 u){ return __uint_as_float(((unsigned int)u)<<16); }
DEVFN u16 f2b(float f){ unsigned int x = __float_as_uint(f); x += 0x7FFFu + ((x>>16)&1u); return (u16)(x>>16); }
DEVFN float fastrcp(float x){ return __builtin_amdgcn_rcpf(x); }

#define GN_INV (1.f/147456.f)

// Per-block GroupNorm scale/shift prologue: 512 (b,c) entries from raw stats.
// Bitwise-identical math to the old make_ss kernel, amortized per block.
DEVFN void gn_prologue(const float* __restrict__ stats, const float* __restrict__ gw,
                       const float* __restrict__ gb, float* scs, float* shs, int tid, int nthr)
{
    for (int i = tid; i < 512; i += nthr) {
        int b = i >> 7, c = i & 127, gn = c >> 4;
        float s = stats[b*16 + gn], q = stats[b*16 + 8 + gn];
        float mu = s * GN_INV, var = fmaxf(q * GN_INV - mu*mu, 0.f);
        float rstd = rsqrtf(var + 1e-5f);
        float scale = rstd * gw[c];
        scs[i] = scale;
        shs[i] = gb[c] - mu * scale;
    }
}

// ---------------------------------------------------------------------------
// Batched fp32 -> bf16 cast. dup=1: output is [.][256] with
// d[(r<<8)+k] = f2b(0.5*s[(r<<7)+(k&127)])  (duplicated, halved weights for
// the fused direction-mean GEMMs).
// ---------------------------------------------------------------------------
struct CastArgs { const float* s[8]; u16* d[8]; int n[8]; int dup[8]; };
__global__ void castf2b_g(CastArgs a)
{
    int p = blockIdx.y;
    int i = blockIdx.x*256 + threadIdx.x;
    if (i >= a.n[p]) return;
    if (a.dup[p]) {
        int src = ((i >> 8) << 7) + (i & 127);
        a.d[p][i] = f2b(0.5f * a.s[p][src]);
    } else {
        a.d[p][i] = f2b(a.s[p][i]);
    }
}

// ---------------------------------------------------------------------------
// Batched whh fp32 -> i8 per-row quantization (blockIdx.y=p, 1 wave per row).
// ---------------------------------------------------------------------------
struct QuantArgs { const float* w[8]; char* q[8]; float* dq[8]; };
__global__ void quant_whh_g(QuantArgs a)
{
    int p = blockIdx.y;
    int row = blockIdx.x;
    int lane = threadIdx.x;
    const float* wr = a.w[p] + (long long)row*128;
    float v0 = wr[lane], v1 = wr[lane+64];
    float m = fmaxf(fabsf(v0), fabsf(v1));
#pragma unroll
    for (int off = 32; off; off >>= 1) m = fmaxf(m, __shfl_xor(m, off));
    float s = (m > 0.f) ? m * (1.f/127.f) : 1.f;
    float inv = 1.f / s;
    a.q[p][(long long)row*128 + lane]      = (char)__float2int_rn(v0 * inv);
    a.q[p][(long long)row*128 + lane + 64] = (char)__float2int_rn(v1 * inv);
    if (lane == 0) a.dq[p][row] = s * (1.f/127.f);
}

// ---------------------------------------------------------------------------
// Generic bf16 GEMM: C[M,N] = A[M,K] * B[N,K]^T (+bias[N]) (+PReLU) (+GN stats)
// BK=64 K-step with T2 XOR-swizzle (bank-conflict-free, verified R9:
// SQ_LDS_BANK_CONFLICT=0). XCD-chunked block swizzle (T1/m204, verified R10:
// FETCH 119->~50 MB, gemm dropped below gru in profile).
// __launch_bounds__(256,4): R10 occupancy was ~19% (~1.5-2 blocks/CU) while
// resources allow 4 blocks/CU (33 KB LDS, VGPR 88 <= 128-cap); the GEMM is
// latency-bound on the K-step load->barrier->MFMA round trip, so co-resident
// blocks are the overlap mechanism.
// K must be a multiple of 64. gmode: 0 linear A; 1 stage-B gather; 2 comb
// gather (k<256 from gSrc1, else gSrc2).
// ---------------------------------------------------------------------------
__global__ __launch_bounds__(256, 4)
void gemm_bt(const u16* __restrict__ A, const u16* __restrict__ B,
             const float* __restrict__ bias, u16* __restrict__ C,
             int K, int N,
             long long zA, long long zB, long long zBias, long long zC,
             const float* __restrict__ alphaP, float* __restrict__ stats, int rowsPerB,
             const u16* __restrict__ Ax, const u16* __restrict__ Bx,
             const float* __restrict__ biasx, u16* __restrict__ Cx, int zHalf,
             int gmode, const u16* __restrict__ gSrc1, const u16* __restrict__ gSrc2)
{
    __shared__ __align__(16) u16 As[128*64];
    __shared__ __align__(16) u16 Bs[128*64];
    __shared__ float sstat[16];

    const int tid  = threadIdx.x;
    const int wave = tid >> 6, lane = tid & 63;
    const int quad = lane >> 4, l16 = lane & 15;
    const int wm = wave & 1, wn = wave >> 1;

    long long z = blockIdx.z;
    bool second = false;
    const u16* Ap = A; const u16* Bp = B; const float* bp = bias; u16* Cp = C;
    if (Ax && z >= zHalf) { second = true; Ap = Ax; Bp = Bx; bp = biasx; Cp = Cx; z -= zHalf; }
    Ap += z * zA; Bp += z * zB; Cp += z * zC;
    if (bp) bp += z * zBias;

    const int lin0 = blockIdx.y * gridDim.x + blockIdx.x;
    const int nwg  = gridDim.x * gridDim.y;
    const int lin  = ((nwg & 7) == 0) ? ((lin0 & 7) * (nwg >> 3) + (lin0 >> 3)) : lin0;
    const int mBase = (lin / gridDim.y) * 128;
    const int nBase = (lin % gridDim.y) * 128;

    const int srow = lane >> 3;                  // 0..7 (8 rows/wave/issue)
    const int swk  = ((lane & 7) ^ srow) * 8;    // pre-swizzled source k-off (u16)
    const int nK = K >> 6;

    // Gather-mode per-lane source bases (one address calc before the K-loop).
    const u16* gb[4];
    const u16* gb2[4];
    if (gmode) {
#pragma unroll
        for (int q = 0; q < 4; q++) {
            const int row = mBase + wave*32 + q*8 + srow;
            if (gmode == 1) {
                const int b = row & 3, t = row >> 2;
                long long s0;
                if (!second) { int ih2 = t/96, n = t%96, gs = n/24, iv = n%24;
                               s0 = (long long)gs*9216 + (long long)(iv*96 + (int)z*24 + ih2)*4 + b; }
                else         { int iv = t/96, m = t%96, gs = m/24, ih = m%24;
                               s0 = (long long)gs*9216 + (long long)(ih*96 + (int)z*24 + iv)*4 + b; }
                gb[q] = (second ? gSrc2 : gSrc1) + s0*256;
            } else {
                const int b = row/9216, rem = row%9216, m = rem/96, n = rem%96;
                int gH = m/24, ih = m%24;
                long long sH = (long long)gH*9216 + (long long)(ih*96 + n)*4 + b;
                int gV = n/24, iv = n%24;
                long long sV = (long long)gV*9216 + (long long)(iv*96 + m)*4 + b;
                gb[q]  = gSrc1 + sH*256;
                gb2[q] = gSrc2 + sV*256 - 256;
            }
        }
    }

    f32x4 acc[4][4];
#pragma unroll
    for (int i = 0; i < 4; i++)
#pragma unroll
        for (int j = 0; j < 4; j++) acc[i][j] = (f32x4){0.f,0.f,0.f,0.f};

    for (int kk = 0; kk < nK; ++kk) {
        const int k0 = kk << 6;
#pragma unroll
        for (int q = 0; q < 4; q++) {
            const u16* ga;
            if (gmode == 0)
                ga = Ap + (long long)(mBase + wave*32 + q*8 + srow) * K + k0 + swk;
            else
                ga = ((gmode == 2 && k0 >= 256) ? gb2[q] : gb[q]) + k0 + swk;
            const u16* gbB = Bp + (long long)(nBase + wave*32 + q*8 + srow) * K + k0 + swk;
            __builtin_amdgcn_global_load_lds((const AS_G unsigned int*)ga,
                (AS_L unsigned int*)(As + (wave*32 + q*8)*64), 16, 0, 0);
            __builtin_amdgcn_global_load_lds((const AS_G unsigned int*)gbB,
                (AS_L unsigned int*)(Bs + (wave*32 + q*8)*64), 16, 0, 0);
        }
        __syncthreads();
#pragma unroll
        for (int h = 0; h < 2; h++) {
            bf16x8 af[4], bfr[4];
            const int slot = (((h << 2) | quad) ^ (l16 & 7)) * 8;
#pragma unroll
            for (int mt = 0; mt < 4; mt++) af[mt]  = *(const bf16x8*)(As + (wm*64 + mt*16 + l16)*64 + slot);
#pragma unroll
            for (int nt = 0; nt < 4; nt++) bfr[nt] = *(const bf16x8*)(Bs + (wn*64 + nt*16 + l16)*64 + slot);
#pragma unroll
            for (int mt = 0; mt < 4; mt++)
#pragma unroll
                for (int nt = 0; nt < 4; nt++)
                    acc[mt][nt] = __builtin_amdgcn_mfma_f32_16x16x32_bf16(bfr[nt], af[mt], acc[mt][nt], 0, 0, 0);
        }
        __syncthreads();
    }

    const bool doStats = (stats != nullptr);
    const float alpha = alphaP ? alphaP[0] : 0.f;
    if (doStats) { if (tid < 16) sstat[tid] = 0.f; __syncthreads(); }

    // Swapped layout: lane reg r holds C[row = mBase+wm*64+mt*16+l16]
    //                              [col = nBase+wn*64+nt*16+quad*4+r]
    float lsum[4] = {0,0,0,0}, lsq[4] = {0,0,0,0};
#pragma unroll
    for (int nt = 0; nt < 4; nt++) {
        const int col0 = nBase + wn*64 + nt*16 + quad*4;
        float4 bv4 = {0.f, 0.f, 0.f, 0.f};
        if (bp) bv4 = *(const float4*)(bp + col0);
#pragma unroll
        for (int mt = 0; mt < 4; mt++) {
            const int row = mBase + wm*64 + mt*16 + l16;
            float v0 = acc[mt][nt][0] + bv4.x;
            float v1 = acc[mt][nt][1] + bv4.y;
            float v2 = acc[mt][nt][2] + bv4.z;
            float v3 = acc[mt][nt][3] + bv4.w;
            if (alphaP) {
                v0 = v0 > 0.f ? v0 : alpha * v0;
                v1 = v1 > 0.f ? v1 : alpha * v1;
                v2 = v2 > 0.f ? v2 : alpha * v2;
                v3 = v3 > 0.f ? v3 : alpha * v3;
            }
            if (doStats) {
                lsum[nt] += v0 + v1 + v2 + v3;
                lsq[nt]  += v0*v0 + v1*v1 + v2*v2 + v3*v3;
            }
            uint2 pk;
            pk.x = (unsigned)f2b(v0) | ((unsigned)f2b(v1) << 16);
            pk.y = (unsigned)f2b(v2) | ((unsigned)f2b(v3) << 16);
            *(uint2*)(Cp + (long long)row * N + col0) = pk;
        }
    }
    if (doStats) {
#pragma unroll
        for (int nt = 0; nt < 4; nt++) {
            const int gn = wn*4 + nt;
            atomicAdd(&sstat[gn], lsum[nt]);
            atomicAdd(&sstat[8 + gn], lsq[nt]);
        }
        __syncthreads();
        if (tid < 16) {
            const int b = mBase / rowsPerB;
            atomicAdd(&stats[b*16 + tid], sstat[tid]);
        }
    }
}

// ---------------------------------------------------------------------------
// GRU recurrence (i8 MFMA core), chunk-parallel. 256 blocks = #CUs.
// WARM=32: pessimistic uniform-|J|=0.8 truncation bound 0.8^32 ~ 8e-4, 5x
// below bf16 output rounding; typical decay ~1e-10. (WARM 112->80->48 were
// absmax-invisible, validating the margin.) NS = 176 steps; since 176 is a
// half-multiple of the 32-step loop iteration, the tail break after the
// bank-0 flush skips the final 16 garbage steps.
// ---------------------------------------------------------------------------
#define HSB 144     // h row stride in bytes (128 i8 + 16 pad, 16B aligned)
#define BURST 16
#define NCHUNK 16
#define CHUNK  144  // 2304 / NCHUNK
#define WARM   32   // warm-up steps; WARM + CHUNK multiple of BURST

__global__ __launch_bounds__(512, 2)
void gru_rec(const u16* __restrict__ gxH, const u16* __restrict__ gxV,
             const char* __restrict__ qwH, const char* __restrict__ qwV,
             const float* __restrict__ dqH, const float* __restrict__ dqV,
             const float* __restrict__ bhhH, const float* __restrict__ bhhV,
             u16* __restrict__ outH, u16* __restrict__ outV)
{
    const int id    = blockIdx.x / NCHUNK;   // (stack, group, dir)
    const int chunk = blockIdx.x % NCHUNK;
    const int stack = id >> 3, g = (id >> 1) & 3, d = id & 1;
    const u16*  gx  = (stack ? gxV : gxH) + (long long)g*9216*768 + d*384;
    const char* qw  = (stack ? qwV : qwH) + (long long)(g*2 + d)*384*128;
    const float* dqv = (stack ? dqV : dqH) + (g*2 + d)*384;
    const float* bhh = (stack ? bhhV : bhhH) + (g*2 + d)*384;
    u16* out = (stack ? outV : outH) + (long long)g*9216*256 + d*128;

    const int sBegin = chunk * CHUNK;        // first step whose output we own
    const int sEnd   = sBegin + CHUNK;       // one past last
    const int sw     = (chunk == 0) ? 0 : sBegin - WARM;  // warm-up start

    const int tid = threadIdx.x;
    const int w = tid >> 6, lane = tid & 63;
    const int quad = lane >> 4, l16 = lane & 15;

    __shared__ __align__(16) char hbf8[2][16*HSB];   // 4.6 KB
    __shared__ __align__(16) u16 outs[2][BURST*512]; // 32 KB
    for (int i = tid; i < 2*16*HSB; i += 512) ((char*)hbf8)[i] = 0;

    const int col = w*16 + l16;
    i32x4 ifrag[3][2];
#pragma unroll
    for (int gate = 0; gate < 3; ++gate)
#pragma unroll
        for (int kc = 0; kc < 2; ++kc)
            ifrag[gate][kc] = *(const i32x4*)(qw + (long long)(gate*128 + col)*128 + kc*64 + quad*16);

    const float dqR = dqv[col], dqZ = dqv[128 + col], dqN = dqv[256 + col];
    const float bhr = bhh[col], bhz = bhh[128 + col], bhn = bhh[256 + col];
    float h = 0.f;

    const int step = d ? -1 : 1;
    const int t0 = d ? 2303 : 0;
    const long long rowStride = (long long)step * 3072;

    u16 bankA[BURST][3], bankB[BURST][3];
    const i32x4 zi = {0,0,0,0};

    auto loadBank = [&](u16 (&bk)[BURST][3], int sbase) {
        if (sbase >= sEnd) return;     // banks are 16-aligned: all-in or all-out
        const u16* p = gx + (long long)((t0 + step*sbase)*4 + quad)*768 + col;
#pragma unroll
        for (int j = 0; j < BURST; j++) {
            bk[j][0] = p[0]; bk[j][1] = p[128]; bk[j][2] = p[256];
            p += rowStride;
        }
    };

    auto flushOut = [&](int sbase, int bank) {
        const u16* ob = outs[bank];
#pragma unroll
        for (int c = 0; c < 2; c++) {
            const int lin = (tid + c*512) * 8;
            const int s   = lin >> 9;
            const int rem = lin & 511;
            const int q   = rem >> 7, cc = rem & 127;
            const int tt  = t0 + step * (sbase + s);
            *(uint4*)(out + (long long)(tt*4 + q)*256 + cc) = *(const uint4*)(ob + lin);
        }
    };

    // LDS-only barrier: burst-prefetch global loads stay in flight.
    auto ldsbar = [&]() {
        asm volatile("s_waitcnt lgkmcnt(0)\n\ts_barrier" ::: "memory");
    };

    auto stepf = [&](int j, int bank, u16 g0, u16 g1, u16 g2) {
        const char* hb = hbf8[j & 1];
        char* hw = (char*)hbf8[(j + 1) & 1];
        i32x4 a0 = *(const i32x4*)(hb + l16*HSB + quad*16);
        i32x4 a1 = *(const i32x4*)(hb + l16*HSB + 64 + quad*16);
        i32x4 aR = __builtin_amdgcn_mfma_i32_16x16x64_i8(a0, ifrag[0][0], zi, 0, 0, 0);
        i32x4 aZ = __builtin_amdgcn_mfma_i32_16x16x64_i8(a0, ifrag[1][0], zi, 0, 0, 0);
        i32x4 aN = __builtin_amdgcn_mfma_i32_16x16x64_i8(a0, ifrag[2][0], zi, 0, 0, 0);
        aR = __builtin_amdgcn_mfma_i32_16x16x64_i8(a1, ifrag[0][1], aR, 0, 0, 0);
        aZ = __builtin_amdgcn_mfma_i32_16x16x64_i8(a1, ifrag[1][1], aZ, 0, 0, 0);
        aN = __builtin_amdgcn_mfma_i32_16x16x64_i8(a1, ifrag[2][1], aN, 0, 0, 0);
        // lane reads C[row = 4*quad (reg 0)][col = l16] -> (batch quad, this col)
        float r  = fastrcp(1.f + __expf(-(b2f(g0) + bhr + (float)aR[0] * dqR)));
        float zz = fastrcp(1.f + __expf(-(b2f(g1) + bhz + (float)aZ[0] * dqZ)));
        float nn = b2f(g2) + r * ((float)aN[0] * dqN + bhn);
        nn = 1.f - 2.f * fastrcp(__expf(2.f * nn) + 1.f);   // tanh
        h = zz * (h - nn) + nn;
        hw[4*quad*HSB + col] = (char)__float2int_rn(h * 127.f);
        outs[bank][j*512 + quad*128 + col] = f2b(h);
        ldsbar();
    };

    loadBank(bankA, sw);
    __syncthreads();   // hbf8 zero visible + bankA drained

    for (int base = sw; base < sEnd; base += 2*BURST) {
        loadBank(bankB, base + BURST);
#pragma unroll
        for (int j = 0; j < BURST; j++) stepf(j, 0, bankA[j][0], bankA[j][1], bankA[j][2]);
        if (base >= sBegin) flushOut(base, 0);               // base < sEnd by loop cond
        if (base + BURST >= sEnd) break;                     // half-iteration tail
        loadBank(bankA, base + 2*BURST);
#pragma unroll
        for (int j = 0; j < BURST; j++) stepf(j, 1, bankB[j][0], bankB[j][1], bankB[j][2]);
        const int b2s = base + BURST;
        if (b2s >= sBegin) flushOut(b2s, 1);
    }
}

// ---------------------------------------------------------------------------
// Small helper kernels (fp32 external boundaries)
// ---------------------------------------------------------------------------
__global__ void repack_w(const float* __restrict__ w1, const float* __restrict__ w2,
                         const float* __restrict__ wc,
                         u16* __restrict__ w1r, u16* __restrict__ w2r, u16* __restrict__ wcr)
{
    int idx = blockIdx.x*256 + threadIdx.x;
    if (idx < 128*1152) {
        int o = idx / 1152, k = idx % 1152, tap = k >> 7, ci = k & 127;
        w2r[idx] = f2b(w2[(o*128 + ci)*9 + tap]);
    }
    // w1r: 128x64, zero-padded past k=27 (conv1 GEMM runs K=64, exact)
    if (idx < 128*64) {
        int o = idx >> 6, k = idx & 63;
        float v = 0.f;
        if (k < 27) { int tap = k/3, ci = k - tap*3; v = w1[(o*3 + ci)*9 + tap]; }
        w1r[idx] = f2b(v);
    }
    // wcr: 128x512 dup'd+halved for the fused comb GEMM (K=512):
    // B'[o,k] = 0.5*wc[o, ((k>=256)?128:0) + (k&127)]
    if (idx < 128*512) {
        int o = idx >> 9, k = idx & 511;
        int c = ((k >> 8) << 7) + (k & 127);
        wcr[idx] = f2b(0.5f * wc[o*256 + c]);
    }
}

__global__ void im2col1(const float* __restrict__ x, u16* __restrict__ A1)
{
    int row = blockIdx.x*256 + threadIdx.x;
    if (row >= 36864) return;
    int b = row / 9216, rem = row % 9216, m = rem / 96, n = rem % 96;
    u16* dst = A1 + (long long)row*64;
#pragma unroll
    for (int k = 0; k < 64; k++) {
        float v = 0.f;
        if (k < 27) {
            int tap = k/3, ci = k - tap*3;
            int mm = m + tap/3 - 1, nn = n + tap%3 - 1;
            if (mm >= 0 && mm < 96 && nn >= 0 && nn < 96)
                v = x[((b*3 + ci)*96 + mm)*96 + nn];
        }
        dst[k] = f2b(v);
    }
}

// Vectorized x8 + inline GroupNorm scale/shift (make_ss folded; LDS table).
__global__ void im2col2(const u16* __restrict__ buf1, const float* __restrict__ stats,
                        const float* __restrict__ gw, const float* __restrict__ gb,
                        u16* __restrict__ A2)
{
    __shared__ float scs[512], shs[512];
    gn_prologue(stats, gw, gb, scs, shs, threadIdx.x, 256);
    __syncthreads();

    int idx = blockIdx.x*256 + threadIdx.x;     // 5,308,416 = 36864*144 exact
    int row = idx / 144, q = idx % 144;
    int tap = q >> 4, ci0 = (q & 15) << 3;
    int b = row / 9216, rem = row % 9216, m = rem / 96, n = rem % 96;
    int mm = m + tap/3 - 1, nn = n + tap%3 - 1;
    bf16x8 o = (bf16x8){0,0,0,0,0,0,0,0};
    if (mm >= 0 && mm < 96 && nn >= 0 && nn < 96) {
        bf16x8 v = *(const bf16x8*)(buf1 + (long long)(b*9216 + mm*96 + nn)*128 + ci0);
#pragma unroll
        for (int j = 0; j < 8; j++)
            o[j] = (short)f2b(b2f((u16)v[j]) * scs[b*128 + ci0 + j] + shs[b*128 + ci0 + j]);
    }
    *(bf16x8*)(A2 + (long long)row*1152 + tap*128 + ci0) = o;
}

// Vectorized x8 + inline GroupNorm scale/shift. 589824 threads.
__global__ void repack_seq(const u16* __restrict__ buf2, const float* __restrict__ stats,
                           const float* __restrict__ gw, const float* __restrict__ gb,
                           u16* __restrict__ xh, u16* __restrict__ xv)
{
    __shared__ float scs[512], shs[512];
    gn_prologue(stats, gw, gb, scs, shs, threadIdx.x, 256);
    __syncthreads();

    int idx = blockIdx.x*256 + threadIdx.x;
    int c0 = (idx & 15) << 3, r1 = idx >> 4;
    int b = r1 & 3, r2 = r1 >> 2;
    int t = r2 % 2304, g = r2 / 2304;
    int iw = t / 96, pos = t % 96;
    int rowH = b*9216 + (g*24 + iw)*96 + pos;
    int rowV = b*9216 + pos*96 + (g*24 + iw);
    bf16x8 vh = *(const bf16x8*)(buf2 + (long long)rowH*128 + c0);
    bf16x8 vv = *(const bf16x8*)(buf2 + (long long)rowV*128 + c0);
    bf16x8 oh, ov;
#pragma unroll
    for (int j = 0; j < 8; j++) {
        float scale = scs[b*128 + c0 + j], shift = shs[b*128 + c0 + j];
        oh[j] = (short)f2b(b2f((u16)vh[j]) * scale + shift);
        ov[j] = (short)f2b(b2f((u16)vv[j]) * scale + shift);
    }
    *(bf16x8*)(xh + ((long long)r1 << 7) + c0) = oh;
    *(bf16x8*)(xv + ((long long)r1 << 7) + c0) = ov;
}

// Final: GroupNorm (inline scale/shift) + NCHW transpose to fp32 out.
__global__ void final_kernel(const u16* __restrict__ p3, const float* __restrict__ stats,
                             const float* __restrict__ gw, const float* __restrict__ gb,
                             float* __restrict__ out)
{
    __shared__ float tile[128*97];
    __shared__ float scs[512], shs[512];
    gn_prologue(stats, gw, gb, scs, shs, threadIdx.x, 256);
    __syncthreads();

    int bm = blockIdx.x;
    int b = bm / 96, m = bm % 96;
    int tid = threadIdx.x;
    int rowbase = b*9216 + m*96;
    for (int idx = tid; idx < 96*128; idx += 256) {
        int n = idx >> 7, o = idx & 127;
        float v = b2f(p3[(long long)(rowbase + n)*128 + o]);
        tile[o*97 + n] = v * scs[b*128 + o] + shs[b*128 + o];
    }
    __syncthreads();
    for (int idx = tid; idx < 96*128; idx += 256) {
        int o = idx / 96, n = idx % 96;
        out[((long long)(b*128 + o)*96 + m)*96 + n] = tile[o*97 + n];
    }
}

// ---------------------------------------------------------------------------
extern "C" void kernel_launch(void* const* d_in, const int* in_sizes, int n_in,
                              void* d_out, int out_size, void* d_ws, size_t ws_size,
                              hipStream_t stream)
{
    (void)in_sizes; (void)n_in; (void)out_size;
    auto F = [&](int i){ return (const float*)d_in[i]; };

    char* ws = (char*)d_ws;
    size_t off = 0;
    auto alloc = [&](size_t bytes)->char* {
        char* p = ws + off;
        off += (bytes + 255) & ~(size_t)255;
        return p;
    };

    float* stats = (float*)alloc(3*64*sizeof(float));
    u16* w1r  = (u16*)alloc((size_t)128*64*2);
    u16* w2r  = (u16*)alloc((size_t)128*1152*2);
    u16* wcr  = (u16*)alloc((size_t)128*512*2);   // dup'd+halved, K=512
    u16 *wih0c[4], *wih1c[4];
    char *qw0[4], *qw1[4];
    float *dq0[4], *dq1[4];
    for (int p = 0; p < 4; p++) {
        // p=2,3 (stage-B wih0) hold the dup'd 768x256 version -> 786432 u16
        wih0c[p] = (u16*)alloc((size_t)(p < 2 ? 393216 : 786432)*2);
        wih1c[p] = (u16*)alloc((size_t)786432*2);
        qw0[p]   = (char*)alloc((size_t)393216);
        qw1[p]   = (char*)alloc((size_t)393216);
        dq0[p]   = (float*)alloc((size_t)3072*4);
        dq1[p]   = (float*)alloc((size_t)3072*4);
    }
    u16* A1   = (u16*)alloc((size_t)36864*64*2);
    u16* buf1 = (u16*)alloc((size_t)36864*128*2);
    u16* buf2 = (u16*)alloc((size_t)36864*128*2);
    u16* xh   = (u16*)alloc((size_t)4718592*2);
    u16* xv   = (u16*)alloc((size_t)4718592*2);
    u16* gxH  = (u16*)alloc((size_t)4*9216*768*2);
    u16* gxV  = (u16*)alloc((size_t)4*9216*768*2);
    u16* z1H  = (u16*)alloc((size_t)4*9216*256*2);
    u16* z1V  = (u16*)alloc((size_t)4*9216*256*2);

    u16* A2  = gxH;
    u16* y0H = xh;
    u16* y0V = buf1;
    u16* p3  = buf1;

    if (ws_size < off) return;

    hipMemsetAsync(stats, 0, 3*64*sizeof(float), stream);
    repack_w<<<576, 256, 0, stream>>>(F(1), F(6), F(11), w1r, w2r, wcr);
    im2col1<<<144, 256, 0, stream>>>(F(0), A1);

    CastArgs ca;
    QuantArgs qa;
    for (int p = 0; p < 4; p++) {
        int base = 16 + p*8;
        ca.s[p]   = F(base+0); ca.d[p]   = wih0c[p];
        ca.n[p]   = (p < 2) ? 393216 : 786432;
        ca.dup[p] = (p < 2) ? 0 : 1;
        ca.s[p+4] = F(base+4); ca.d[p+4] = wih1c[p]; ca.n[p+4] = 786432; ca.dup[p+4] = 0;
        qa.w[p]   = F(base+1); qa.q[p]   = qw0[p];   qa.dq[p]   = dq0[p];
        qa.w[p+4] = F(base+5); qa.q[p+4] = qw1[p];   qa.dq[p+4] = dq1[p];
    }
    castf2b_g<<<dim3(3072, 8), 256, 0, stream>>>(ca);
    quant_whh_g<<<dim3(3072, 8), 64, 0, stream>>>(qa);

    gemm_bt<<<dim3(288,1,1), 256, 0, stream>>>(A1, w1r, F(2), buf1, 64, 128,
        0,0,0,0, F(3), stats + 0, 9216, nullptr, nullptr, nullptr, nullptr, 0,
        0, nullptr, nullptr);

    im2col2<<<20736, 256, 0, stream>>>(buf1, stats + 0, F(4), F(5), A2);
    gemm_bt<<<dim3(288,1,1), 256, 0, stream>>>(A2, w2r, F(7), buf2, 1152, 128,
        0,0,0,0, F(8), stats + 64, 9216, nullptr, nullptr, nullptr, nullptr, 0,
        0, nullptr, nullptr);

    repack_seq<<<2304, 256, 0, stream>>>(buf2, stats + 64, F(9), F(10), xh, xv);

    const long long zA0 = 9216LL*128, zA1 = 9216LL*256;
    const long long zB0 = 768LL*128,  zB1 = 768LL*256;
    const long long zC  = 9216LL*768;

    // ---- Stage A ---- (H and V pairs merged into single launches, z=8)
    gemm_bt<<<dim3(72,6,8), 256, 0, stream>>>(xh, wih0c[0], F(18), gxH, 128, 768, zA0, zB0, 768, zC,
        nullptr, nullptr, 0, xv, wih0c[1], F(26), gxV, 4, 0, nullptr, nullptr);
    gru_rec<<<16*NCHUNK, 512, 0, stream>>>(gxH, gxV, qw0[0], qw0[1], dq0[0], dq0[1], F(19), F(27), y0H, y0V);
    gemm_bt<<<dim3(72,6,8), 256, 0, stream>>>(y0H, wih1c[0], F(22), gxH, 256, 768, zA1, zB1, 768, zC,
        nullptr, nullptr, 0, y0V, wih1c[1], F(30), gxV, 4, 0, nullptr, nullptr);
    gru_rec<<<16*NCHUNK, 512, 0, stream>>>(gxH, gxV, qw1[0], qw1[1], dq1[0], dq1[1], F(23), F(31), z1H, z1V);

    // ---- Stage B ---- (repack_B fused into the GEMM via A-row gather +
    // dup'd/halved weights: K=256, direction-mean folded into the MFMA)
    gemm_bt<<<dim3(72,6,8), 256, 0, stream>>>(z1H, wih0c[2], F(34), gxH, 256, 768, 0, 768LL*256, 768, zC,
        nullptr, nullptr, 0, z1H, wih0c[3], F(42), gxV, 4, 1, z1V, z1H);
    gru_rec<<<16*NCHUNK, 512, 0, stream>>>(gxH, gxV, qw0[2], qw0[3], dq0[2], dq0[3], F(35), F(43), y0H, y0V);
    gemm_bt<<<dim3(72,6,8), 256, 0, stream>>>(y0H, wih1c[2], F(38), gxH, 256, 768, zA1, zB1, 768, zC,
        nullptr, nullptr, 0, y0V, wih1c[3], F(46), gxV, 4, 0, nullptr, nullptr);
    gru_rec<<<16*NCHUNK, 512, 0, stream>>>(gxH, gxV, qw1[2], qw1[3], dq1[2], dq1[3], F(39), F(47), z1H, z1V);

    // ---- combine ---- (repack_comb fused: K=512 gather from z1H/z1V)
    gemm_bt<<<dim3(288,1,1), 256, 0, stream>>>(z1H, wcr, F(12), p3, 512, 128,
        0,0,0,0, F(13), stats + 128, 9216, nullptr, nullptr, nullptr, nullptr, 0,
        2, z1H, z1V);
    final_kernel<<<384, 256, 0, stream>>>(p3, stats + 128, F(14), F(15), (float*)d_out);
}

// Round 12
// 828.642 us; speedup vs baseline: 1.0934x; 1.0934x over previous
//
#include <hip/hip_runtime.h>

typedef unsigned short u16;
typedef __attribute__((ext_vector_type(8))) short bf16x8;
typedef __attribute__((ext_vector_type(4))) float f32x4;
typedef __attribute__((ext_vector_type(4))) int   i32x4;

#define DEVFN static __device__ __forceinline__
#define AS_G __attribute__((address_space(1)))
#define AS_L __attribute__((address_space(3)))

DEVFN float b2f(u16 u){ return __uint_as_float(((unsigned int)u)<<16); }
DEVFN u16 f2b(float f){ unsigned int x = __float_as_uint(f); x += 0x7FFFu + ((x>>16)&1u); return (u16)(x>>16); }
DEVFN float fastrcp(float x){ return __builtin_amdgcn_rcpf(x); }

#define GN_INV (1.f/147456.f)

// Per-block GroupNorm scale/shift prologue: 512 (b,c) entries from raw stats.
// Bitwise-identical math to the old make_ss kernel, amortized per block.
DEVFN void gn_prologue(const float* __restrict__ stats, const float* __restrict__ gw,
                       const float* __restrict__ gb, float* scs, float* shs, int tid, int nthr)
{
    for (int i = tid; i < 512; i += nthr) {
        int b = i >> 7, c = i & 127, gn = c >> 4;
        float s = stats[b*16 + gn], q = stats[b*16 + 8 + gn];
        float mu = s * GN_INV, var = fmaxf(q * GN_INV - mu*mu, 0.f);
        float rstd = rsqrtf(var + 1e-5f);
        float scale = rstd * gw[c];
        scs[i] = scale;
        shs[i] = gb[c] - mu * scale;
    }
}

// ---------------------------------------------------------------------------
// Batched fp32 -> bf16 cast. dup=1: output is [.][256] with
// d[(r<<8)+k] = f2b(0.5*s[(r<<7)+(k&127)])  (duplicated, halved weights for
// the fused direction-mean GEMMs).
// ---------------------------------------------------------------------------
struct CastArgs { const float* s[8]; u16* d[8]; int n[8]; int dup[8]; };
__global__ void castf2b_g(CastArgs a)
{
    int p = blockIdx.y;
    int i = blockIdx.x*256 + threadIdx.x;
    if (i >= a.n[p]) return;
    if (a.dup[p]) {
        int src = ((i >> 8) << 7) + (i & 127);
        a.d[p][i] = f2b(0.5f * a.s[p][src]);
    } else {
        a.d[p][i] = f2b(a.s[p][i]);
    }
}

// ---------------------------------------------------------------------------
// Batched whh fp32 -> i8 per-row quantization (blockIdx.y=p, 1 wave per row).
// ---------------------------------------------------------------------------
struct QuantArgs { const float* w[8]; char* q[8]; float* dq[8]; };
__global__ void quant_whh_g(QuantArgs a)
{
    int p = blockIdx.y;
    int row = blockIdx.x;
    int lane = threadIdx.x;
    const float* wr = a.w[p] + (long long)row*128;
    float v0 = wr[lane], v1 = wr[lane+64];
    float m = fmaxf(fabsf(v0), fabsf(v1));
#pragma unroll
    for (int off = 32; off; off >>= 1) m = fmaxf(m, __shfl_xor(m, off));
    float s = (m > 0.f) ? m * (1.f/127.f) : 1.f;
    float inv = 1.f / s;
    a.q[p][(long long)row*128 + lane]      = (char)__float2int_rn(v0 * inv);
    a.q[p][(long long)row*128 + lane + 64] = (char)__float2int_rn(v1 * inv);
    if (lane == 0) a.dq[p][row] = s * (1.f/127.f);
}

// ---------------------------------------------------------------------------
// Generic bf16 GEMM: C[M,N] = A[M,K] * B[N,K]^T (+bias[N]) (+PReLU) (+GN stats)
// BK=64 K-step with T2 XOR-swizzle (bank-conflict-free, verified R9:
// SQ_LDS_BANK_CONFLICT=0). XCD-chunked block swizzle (T1/m204, verified R10:
// FETCH 119->53 MB, gemm dropped below gru in profile).
// NOTE (R11 post-mortem): __launch_bounds__(256,4) REGRESSED — forced VGPR
// 88->64 (ILP loss: MfmaUtil 13.5->11.5, VALUBusy 30->18.5) and doubled
// WRITE_SIZE (129->237 MB: 2x C tiles in flight -> partial-line evictions of
// the 8B uint2 stores). Occupancy is NOT this kernel's limiter; keep plain
// __launch_bounds__(256).
// K must be a multiple of 64. gmode: 0 linear A; 1 stage-B gather; 2 comb
// gather (k<256 from gSrc1, else gSrc2).
// ---------------------------------------------------------------------------
__global__ __launch_bounds__(256)
void gemm_bt(const u16* __restrict__ A, const u16* __restrict__ B,
             const float* __restrict__ bias, u16* __restrict__ C,
             int K, int N,
             long long zA, long long zB, long long zBias, long long zC,
             const float* __restrict__ alphaP, float* __restrict__ stats, int rowsPerB,
             const u16* __restrict__ Ax, const u16* __restrict__ Bx,
             const float* __restrict__ biasx, u16* __restrict__ Cx, int zHalf,
             int gmode, const u16* __restrict__ gSrc1, const u16* __restrict__ gSrc2)
{
    __shared__ __align__(16) u16 As[128*64];
    __shared__ __align__(16) u16 Bs[128*64];
    __shared__ float sstat[16];

    const int tid  = threadIdx.x;
    const int wave = tid >> 6, lane = tid & 63;
    const int quad = lane >> 4, l16 = lane & 15;
    const int wm = wave & 1, wn = wave >> 1;

    long long z = blockIdx.z;
    bool second = false;
    const u16* Ap = A; const u16* Bp = B; const float* bp = bias; u16* Cp = C;
    if (Ax && z >= zHalf) { second = true; Ap = Ax; Bp = Bx; bp = biasx; Cp = Cx; z -= zHalf; }
    Ap += z * zA; Bp += z * zB; Cp += z * zC;
    if (bp) bp += z * zBias;

    const int lin0 = blockIdx.y * gridDim.x + blockIdx.x;
    const int nwg  = gridDim.x * gridDim.y;
    const int lin  = ((nwg & 7) == 0) ? ((lin0 & 7) * (nwg >> 3) + (lin0 >> 3)) : lin0;
    const int mBase = (lin / gridDim.y) * 128;
    const int nBase = (lin % gridDim.y) * 128;

    const int srow = lane >> 3;                  // 0..7 (8 rows/wave/issue)
    const int swk  = ((lane & 7) ^ srow) * 8;    // pre-swizzled source k-off (u16)
    const int nK = K >> 6;

    // Gather-mode per-lane source bases (one address calc before the K-loop).
    const u16* gb[4];
    const u16* gb2[4];
    if (gmode) {
#pragma unroll
        for (int q = 0; q < 4; q++) {
            const int row = mBase + wave*32 + q*8 + srow;
            if (gmode == 1) {
                const int b = row & 3, t = row >> 2;
                long long s0;
                if (!second) { int ih2 = t/96, n = t%96, gs = n/24, iv = n%24;
                               s0 = (long long)gs*9216 + (long long)(iv*96 + (int)z*24 + ih2)*4 + b; }
                else         { int iv = t/96, m = t%96, gs = m/24, ih = m%24;
                               s0 = (long long)gs*9216 + (long long)(ih*96 + (int)z*24 + iv)*4 + b; }
                gb[q] = (second ? gSrc2 : gSrc1) + s0*256;
            } else {
                const int b = row/9216, rem = row%9216, m = rem/96, n = rem%96;
                int gH = m/24, ih = m%24;
                long long sH = (long long)gH*9216 + (long long)(ih*96 + n)*4 + b;
                int gV = n/24, iv = n%24;
                long long sV = (long long)gV*9216 + (long long)(iv*96 + m)*4 + b;
                gb[q]  = gSrc1 + sH*256;
                gb2[q] = gSrc2 + sV*256 - 256;
            }
        }
    }

    f32x4 acc[4][4];
#pragma unroll
    for (int i = 0; i < 4; i++)
#pragma unroll
        for (int j = 0; j < 4; j++) acc[i][j] = (f32x4){0.f,0.f,0.f,0.f};

    for (int kk = 0; kk < nK; ++kk) {
        const int k0 = kk << 6;
#pragma unroll
        for (int q = 0; q < 4; q++) {
            const u16* ga;
            if (gmode == 0)
                ga = Ap + (long long)(mBase + wave*32 + q*8 + srow) * K + k0 + swk;
            else
                ga = ((gmode == 2 && k0 >= 256) ? gb2[q] : gb[q]) + k0 + swk;
            const u16* gbB = Bp + (long long)(nBase + wave*32 + q*8 + srow) * K + k0 + swk;
            __builtin_amdgcn_global_load_lds((const AS_G unsigned int*)ga,
                (AS_L unsigned int*)(As + (wave*32 + q*8)*64), 16, 0, 0);
            __builtin_amdgcn_global_load_lds((const AS_G unsigned int*)gbB,
                (AS_L unsigned int*)(Bs + (wave*32 + q*8)*64), 16, 0, 0);
        }
        __syncthreads();
#pragma unroll
        for (int h = 0; h < 2; h++) {
            bf16x8 af[4], bfr[4];
            const int slot = (((h << 2) | quad) ^ (l16 & 7)) * 8;
#pragma unroll
            for (int mt = 0; mt < 4; mt++) af[mt]  = *(const bf16x8*)(As + (wm*64 + mt*16 + l16)*64 + slot);
#pragma unroll
            for (int nt = 0; nt < 4; nt++) bfr[nt] = *(const bf16x8*)(Bs + (wn*64 + nt*16 + l16)*64 + slot);
#pragma unroll
            for (int mt = 0; mt < 4; mt++)
#pragma unroll
                for (int nt = 0; nt < 4; nt++)
                    acc[mt][nt] = __builtin_amdgcn_mfma_f32_16x16x32_bf16(bfr[nt], af[mt], acc[mt][nt], 0, 0, 0);
        }
        __syncthreads();
    }

    const bool doStats = (stats != nullptr);
    const float alpha = alphaP ? alphaP[0] : 0.f;
    if (doStats) { if (tid < 16) sstat[tid] = 0.f; __syncthreads(); }

    // Swapped layout: lane reg r holds C[row = mBase+wm*64+mt*16+l16]
    //                              [col = nBase+wn*64+nt*16+quad*4+r]
    float lsum[4] = {0,0,0,0}, lsq[4] = {0,0,0,0};
#pragma unroll
    for (int nt = 0; nt < 4; nt++) {
        const int col0 = nBase + wn*64 + nt*16 + quad*4;
        float4 bv4 = {0.f, 0.f, 0.f, 0.f};
        if (bp) bv4 = *(const float4*)(bp + col0);
#pragma unroll
        for (int mt = 0; mt < 4; mt++) {
            const int row = mBase + wm*64 + mt*16 + l16;
            float v0 = acc[mt][nt][0] + bv4.x;
            float v1 = acc[mt][nt][1] + bv4.y;
            float v2 = acc[mt][nt][2] + bv4.z;
            float v3 = acc[mt][nt][3] + bv4.w;
            if (alphaP) {
                v0 = v0 > 0.f ? v0 : alpha * v0;
                v1 = v1 > 0.f ? v1 : alpha * v1;
                v2 = v2 > 0.f ? v2 : alpha * v2;
                v3 = v3 > 0.f ? v3 : alpha * v3;
            }
            if (doStats) {
                lsum[nt] += v0 + v1 + v2 + v3;
                lsq[nt]  += v0*v0 + v1*v1 + v2*v2 + v3*v3;
            }
            uint2 pk;
            pk.x = (unsigned)f2b(v0) | ((unsigned)f2b(v1) << 16);
            pk.y = (unsigned)f2b(v2) | ((unsigned)f2b(v3) << 16);
            *(uint2*)(Cp + (long long)row * N + col0) = pk;
        }
    }
    if (doStats) {
#pragma unroll
        for (int nt = 0; nt < 4; nt++) {
            const int gn = wn*4 + nt;
            atomicAdd(&sstat[gn], lsum[nt]);
            atomicAdd(&sstat[8 + gn], lsq[nt]);
        }
        __syncthreads();
        if (tid < 16) {
            const int b = mBase / rowsPerB;
            atomicAdd(&stats[b*16 + tid], sstat[tid]);
        }
    }
}

// ---------------------------------------------------------------------------
// GRU recurrence (i8 MFMA core), chunk-parallel. 256 blocks = #CUs.
// WARM=32 (verified R11: absmax unchanged): pessimistic uniform-|J|=0.8
// truncation bound 0.8^32 ~ 8e-4, 5x below bf16 output rounding; typical
// decay ~1e-10. NS = 176 steps; the tail break after the bank-0 flush skips
// the final 16-step half-iteration.
// ---------------------------------------------------------------------------
#define HSB 144     // h row stride in bytes (128 i8 + 16 pad, 16B aligned)
#define BURST 16
#define NCHUNK 16
#define CHUNK  144  // 2304 / NCHUNK
#define WARM   32   // warm-up steps; WARM + CHUNK multiple of BURST

__global__ __launch_bounds__(512, 2)
void gru_rec(const u16* __restrict__ gxH, const u16* __restrict__ gxV,
             const char* __restrict__ qwH, const char* __restrict__ qwV,
             const float* __restrict__ dqH, const float* __restrict__ dqV,
             const float* __restrict__ bhhH, const float* __restrict__ bhhV,
             u16* __restrict__ outH, u16* __restrict__ outV)
{
    const int id    = blockIdx.x / NCHUNK;   // (stack, group, dir)
    const int chunk = blockIdx.x % NCHUNK;
    const int stack = id >> 3, g = (id >> 1) & 3, d = id & 1;
    const u16*  gx  = (stack ? gxV : gxH) + (long long)g*9216*768 + d*384;
    const char* qw  = (stack ? qwV : qwH) + (long long)(g*2 + d)*384*128;
    const float* dqv = (stack ? dqV : dqH) + (g*2 + d)*384;
    const float* bhh = (stack ? bhhV : bhhH) + (g*2 + d)*384;
    u16* out = (stack ? outV : outH) + (long long)g*9216*256 + d*128;

    const int sBegin = chunk * CHUNK;        // first step whose output we own
    const int sEnd   = sBegin + CHUNK;       // one past last
    const int sw     = (chunk == 0) ? 0 : sBegin - WARM;  // warm-up start

    const int tid = threadIdx.x;
    const int w = tid >> 6, lane = tid & 63;
    const int quad = lane >> 4, l16 = lane & 15;

    __shared__ __align__(16) char hbf8[2][16*HSB];   // 4.6 KB
    __shared__ __align__(16) u16 outs[2][BURST*512]; // 32 KB
    for (int i = tid; i < 2*16*HSB; i += 512) ((char*)hbf8)[i] = 0;

    const int col = w*16 + l16;
    i32x4 ifrag[3][2];
#pragma unroll
    for (int gate = 0; gate < 3; ++gate)
#pragma unroll
        for (int kc = 0; kc < 2; ++kc)
            ifrag[gate][kc] = *(const i32x4*)(qw + (long long)(gate*128 + col)*128 + kc*64 + quad*16);

    const float dqR = dqv[col], dqZ = dqv[128 + col], dqN = dqv[256 + col];
    const float bhr = bhh[col], bhz = bhh[128 + col], bhn = bhh[256 + col];
    float h = 0.f;

    const int step = d ? -1 : 1;
    const int t0 = d ? 2303 : 0;
    const long long rowStride = (long long)step * 3072;

    u16 bankA[BURST][3], bankB[BURST][3];
    const i32x4 zi = {0,0,0,0};

    auto loadBank = [&](u16 (&bk)[BURST][3], int sbase) {
        if (sbase >= sEnd) return;     // banks are 16-aligned: all-in or all-out
        const u16* p = gx + (long long)((t0 + step*sbase)*4 + quad)*768 + col;
#pragma unroll
        for (int j = 0; j < BURST; j++) {
            bk[j][0] = p[0]; bk[j][1] = p[128]; bk[j][2] = p[256];
            p += rowStride;
        }
    };

    auto flushOut = [&](int sbase, int bank) {
        const u16* ob = outs[bank];
#pragma unroll
        for (int c = 0; c < 2; c++) {
            const int lin = (tid + c*512) * 8;
            const int s   = lin >> 9;
            const int rem = lin & 511;
            const int q   = rem >> 7, cc = rem & 127;
            const int tt  = t0 + step * (sbase + s);
            *(uint4*)(out + (long long)(tt*4 + q)*256 + cc) = *(const uint4*)(ob + lin);
        }
    };

    // LDS-only barrier: burst-prefetch global loads stay in flight.
    auto ldsbar = [&]() {
        asm volatile("s_waitcnt lgkmcnt(0)\n\ts_barrier" ::: "memory");
    };

    auto stepf = [&](int j, int bank, u16 g0, u16 g1, u16 g2) {
        const char* hb = hbf8[j & 1];
        char* hw = (char*)hbf8[(j + 1) & 1];
        i32x4 a0 = *(const i32x4*)(hb + l16*HSB + quad*16);
        i32x4 a1 = *(const i32x4*)(hb + l16*HSB + 64 + quad*16);
        i32x4 aR = __builtin_amdgcn_mfma_i32_16x16x64_i8(a0, ifrag[0][0], zi, 0, 0, 0);
        i32x4 aZ = __builtin_amdgcn_mfma_i32_16x16x64_i8(a0, ifrag[1][0], zi, 0, 0, 0);
        i32x4 aN = __builtin_amdgcn_mfma_i32_16x16x64_i8(a0, ifrag[2][0], zi, 0, 0, 0);
        aR = __builtin_amdgcn_mfma_i32_16x16x64_i8(a1, ifrag[0][1], aR, 0, 0, 0);
        aZ = __builtin_amdgcn_mfma_i32_16x16x64_i8(a1, ifrag[1][1], aZ, 0, 0, 0);
        aN = __builtin_amdgcn_mfma_i32_16x16x64_i8(a1, ifrag[2][1], aN, 0, 0, 0);
        // lane reads C[row = 4*quad (reg 0)][col = l16] -> (batch quad, this col)
        float r  = fastrcp(1.f + __expf(-(b2f(g0) + bhr + (float)aR[0] * dqR)));
        float zz = fastrcp(1.f + __expf(-(b2f(g1) + bhz + (float)aZ[0] * dqZ)));
        float nn = b2f(g2) + r * ((float)aN[0] * dqN + bhn);
        nn = 1.f - 2.f * fastrcp(__expf(2.f * nn) + 1.f);   // tanh
        h = zz * (h - nn) + nn;
        hw[4*quad*HSB + col] = (char)__float2int_rn(h * 127.f);
        outs[bank][j*512 + quad*128 + col] = f2b(h);
        ldsbar();
    };

    loadBank(bankA, sw);
    __syncthreads();   // hbf8 zero visible + bankA drained

    for (int base = sw; base < sEnd; base += 2*BURST) {
        loadBank(bankB, base + BURST);
#pragma unroll
        for (int j = 0; j < BURST; j++) stepf(j, 0, bankA[j][0], bankA[j][1], bankA[j][2]);
        if (base >= sBegin) flushOut(base, 0);               // base < sEnd by loop cond
        if (base + BURST >= sEnd) break;                     // half-iteration tail
        loadBank(bankA, base + 2*BURST);
#pragma unroll
        for (int j = 0; j < BURST; j++) stepf(j, 1, bankB[j][0], bankB[j][1], bankB[j][2]);
        const int b2s = base + BURST;
        if (b2s >= sBegin) flushOut(b2s, 1);
    }
}

// ---------------------------------------------------------------------------
// Small helper kernels (fp32 external boundaries)
// ---------------------------------------------------------------------------
__global__ void repack_w(const float* __restrict__ w1, const float* __restrict__ w2,
                         const float* __restrict__ wc,
                         u16* __restrict__ w1r, u16* __restrict__ w2r, u16* __restrict__ wcr)
{
    int idx = blockIdx.x*256 + threadIdx.x;
    if (idx < 128*1152) {
        int o = idx / 1152, k = idx % 1152, tap = k >> 7, ci = k & 127;
        w2r[idx] = f2b(w2[(o*128 + ci)*9 + tap]);
    }
    // w1r: 128x64, zero-padded past k=27 (conv1 GEMM runs K=64, exact)
    if (idx < 128*64) {
        int o = idx >> 6, k = idx & 63;
        float v = 0.f;
        if (k < 27) { int tap = k/3, ci = k - tap*3; v = w1[(o*3 + ci)*9 + tap]; }
        w1r[idx] = f2b(v);
    }
    // wcr: 128x512 dup'd+halved for the fused comb GEMM (K=512):
    // B'[o,k] = 0.5*wc[o, ((k>=256)?128:0) + (k&127)]
    if (idx < 128*512) {
        int o = idx >> 9, k = idx & 511;
        int c = ((k >> 8) << 7) + (k & 127);
        wcr[idx] = f2b(0.5f * wc[o*256 + c]);
    }
}

__global__ void im2col1(const float* __restrict__ x, u16* __restrict__ A1)
{
    int row = blockIdx.x*256 + threadIdx.x;
    if (row >= 36864) return;
    int b = row / 9216, rem = row % 9216, m = rem / 96, n = rem % 96;
    u16* dst = A1 + (long long)row*64;
#pragma unroll
    for (int k = 0; k < 64; k++) {
        float v = 0.f;
        if (k < 27) {
            int tap = k/3, ci = k - tap*3;
            int mm = m + tap/3 - 1, nn = n + tap%3 - 1;
            if (mm >= 0 && mm < 96 && nn >= 0 && nn < 96)
                v = x[((b*3 + ci)*96 + mm)*96 + nn];
        }
        dst[k] = f2b(v);
    }
}

// Vectorized x8 + inline GroupNorm scale/shift (make_ss folded; LDS table).
__global__ void im2col2(const u16* __restrict__ buf1, const float* __restrict__ stats,
                        const float* __restrict__ gw, const float* __restrict__ gb,
                        u16* __restrict__ A2)
{
    __shared__ float scs[512], shs[512];
    gn_prologue(stats, gw, gb, scs, shs, threadIdx.x, 256);
    __syncthreads();

    int idx = blockIdx.x*256 + threadIdx.x;     // 5,308,416 = 36864*144 exact
    int row = idx / 144, q = idx % 144;
    int tap = q >> 4, ci0 = (q & 15) << 3;
    int b = row / 9216, rem = row % 9216, m = rem / 96, n = rem % 96;
    int mm = m + tap/3 - 1, nn = n + tap%3 - 1;
    bf16x8 o = (bf16x8){0,0,0,0,0,0,0,0};
    if (mm >= 0 && mm < 96 && nn >= 0 && nn < 96) {
        bf16x8 v = *(const bf16x8*)(buf1 + (long long)(b*9216 + mm*96 + nn)*128 + ci0);
#pragma unroll
        for (int j = 0; j < 8; j++)
            o[j] = (short)f2b(b2f((u16)v[j]) * scs[b*128 + ci0 + j] + shs[b*128 + ci0 + j]);
    }
    *(bf16x8*)(A2 + (long long)row*1152 + tap*128 + ci0) = o;
}

// Vectorized x8 + inline GroupNorm scale/shift. 589824 threads.
__global__ void repack_seq(const u16* __restrict__ buf2, const float* __restrict__ stats,
                           const float* __restrict__ gw, const float* __restrict__ gb,
                           u16* __restrict__ xh, u16* __restrict__ xv)
{
    __shared__ float scs[512], shs[512];
    gn_prologue(stats, gw, gb, scs, shs, threadIdx.x, 256);
    __syncthreads();

    int idx = blockIdx.x*256 + threadIdx.x;
    int c0 = (idx & 15) << 3, r1 = idx >> 4;
    int b = r1 & 3, r2 = r1 >> 2;
    int t = r2 % 2304, g = r2 / 2304;
    int iw = t / 96, pos = t % 96;
    int rowH = b*9216 + (g*24 + iw)*96 + pos;
    int rowV = b*9216 + pos*96 + (g*24 + iw);
    bf16x8 vh = *(const bf16x8*)(buf2 + (long long)rowH*128 + c0);
    bf16x8 vv = *(const bf16x8*)(buf2 + (long long)rowV*128 + c0);
    bf16x8 oh, ov;
#pragma unroll
    for (int j = 0; j < 8; j++) {
        float scale = scs[b*128 + c0 + j], shift = shs[b*128 + c0 + j];
        oh[j] = (short)f2b(b2f((u16)vh[j]) * scale + shift);
        ov[j] = (short)f2b(b2f((u16)vv[j]) * scale + shift);
    }
    *(bf16x8*)(xh + ((long long)r1 << 7) + c0) = oh;
    *(bf16x8*)(xv + ((long long)r1 << 7) + c0) = ov;
}

// Final: GroupNorm (inline scale/shift) + NCHW transpose to fp32 out.
__global__ void final_kernel(const u16* __restrict__ p3, const float* __restrict__ stats,
                             const float* __restrict__ gw, const float* __restrict__ gb,
                             float* __restrict__ out)
{
    __shared__ float tile[128*97];
    __shared__ float scs[512], shs[512];
    gn_prologue(stats, gw, gb, scs, shs, threadIdx.x, 256);
    __syncthreads();

    int bm = blockIdx.x;
    int b = bm / 96, m = bm % 96;
    int tid = threadIdx.x;
    int rowbase = b*9216 + m*96;
    for (int idx = tid; idx < 96*128; idx += 256) {
        int n = idx >> 7, o = idx & 127;
        float v = b2f(p3[(long long)(rowbase + n)*128 + o]);
        tile[o*97 + n] = v * scs[b*128 + o] + shs[b*128 + o];
    }
    __syncthreads();
    for (int idx = tid; idx < 96*128; idx += 256) {
        int o = idx / 96, n = idx % 96;
        out[((long long)(b*128 + o)*96 + m)*96 + n] = tile[o*97 + n];
    }
}

// ---------------------------------------------------------------------------
extern "C" void kernel_launch(void* const* d_in, const int* in_sizes, int n_in,
                              void* d_out, int out_size, void* d_ws, size_t ws_size,
                              hipStream_t stream)
{
    (void)in_sizes; (void)n_in; (void)out_size;
    auto F = [&](int i){ return (const float*)d_in[i]; };

    char* ws = (char*)d_ws;
    size_t off = 0;
    auto alloc = [&](size_t bytes)->char* {
        char* p = ws + off;
        off += (bytes + 255) & ~(size_t)255;
        return p;
    };

    float* stats = (float*)alloc(3*64*sizeof(float));
    u16* w1r  = (u16*)alloc((size_t)128*64*2);
    u16* w2r  = (u16*)alloc((size_t)128*1152*2);
    u16* wcr  = (u16*)alloc((size_t)128*512*2);   // dup'd+halved, K=512
    u16 *wih0c[4], *wih1c[4];
    char *qw0[4], *qw1[4];
    float *dq0[4], *dq1[4];
    for (int p = 0; p < 4; p++) {
        // p=2,3 (stage-B wih0) hold the dup'd 768x256 version -> 786432 u16
        wih0c[p] = (u16*)alloc((size_t)(p < 2 ? 393216 : 786432)*2);
        wih1c[p] = (u16*)alloc((size_t)786432*2);
        qw0[p]   = (char*)alloc((size_t)393216);
        qw1[p]   = (char*)alloc((size_t)393216);
        dq0[p]   = (float*)alloc((size_t)3072*4);
        dq1[p]   = (float*)alloc((size_t)3072*4);
    }
    u16* A1   = (u16*)alloc((size_t)36864*64*2);
    u16* buf1 = (u16*)alloc((size_t)36864*128*2);
    u16* buf2 = (u16*)alloc((size_t)36864*128*2);
    u16* xh   = (u16*)alloc((size_t)4718592*2);
    u16* xv   = (u16*)alloc((size_t)4718592*2);
    u16* gxH  = (u16*)alloc((size_t)4*9216*768*2);
    u16* gxV  = (u16*)alloc((size_t)4*9216*768*2);
    u16* z1H  = (u16*)alloc((size_t)4*9216*256*2);
    u16* z1V  = (u16*)alloc((size_t)4*9216*256*2);

    u16* A2  = gxH;
    u16* y0H = xh;
    u16* y0V = buf1;
    u16* p3  = buf1;

    if (ws_size < off) return;

    hipMemsetAsync(stats, 0, 3*64*sizeof(float), stream);
    repack_w<<<576, 256, 0, stream>>>(F(1), F(6), F(11), w1r, w2r, wcr);
    im2col1<<<144, 256, 0, stream>>>(F(0), A1);

    CastArgs ca;
    QuantArgs qa;
    for (int p = 0; p < 4; p++) {
        int base = 16 + p*8;
        ca.s[p]   = F(base+0); ca.d[p]   = wih0c[p];
        ca.n[p]   = (p < 2) ? 393216 : 786432;
        ca.dup[p] = (p < 2) ? 0 : 1;
        ca.s[p+4] = F(base+4); ca.d[p+4] = wih1c[p]; ca.n[p+4] = 786432; ca.dup[p+4] = 0;
        qa.w[p]   = F(base+1); qa.q[p]   = qw0[p];   qa.dq[p]   = dq0[p];
        qa.w[p+4] = F(base+5); qa.q[p+4] = qw1[p];   qa.dq[p+4] = dq1[p];
    }
    castf2b_g<<<dim3(3072, 8), 256, 0, stream>>>(ca);
    quant_whh_g<<<dim3(3072, 8), 64, 0, stream>>>(qa);

    gemm_bt<<<dim3(288,1,1), 256, 0, stream>>>(A1, w1r, F(2), buf1, 64, 128,
        0,0,0,0, F(3), stats + 0, 9216, nullptr, nullptr, nullptr, nullptr, 0,
        0, nullptr, nullptr);

    im2col2<<<20736, 256, 0, stream>>>(buf1, stats + 0, F(4), F(5), A2);
    gemm_bt<<<dim3(288,1,1), 256, 0, stream>>>(A2, w2r, F(7), buf2, 1152, 128,
        0,0,0,0, F(8), stats + 64, 9216, nullptr, nullptr, nullptr, nullptr, 0,
        0, nullptr, nullptr);

    repack_seq<<<2304, 256, 0, stream>>>(buf2, stats + 64, F(9), F(10), xh, xv);

    const long long zA0 = 9216LL*128, zA1 = 9216LL*256;
    const long long zB0 = 768LL*128,  zB1 = 768LL*256;
    const long long zC  = 9216LL*768;

    // ---- Stage A ---- (H and V pairs merged into single launches, z=8)
    gemm_bt<<<dim3(72,6,8), 256, 0, stream>>>(xh, wih0c[0], F(18), gxH, 128, 768, zA0, zB0, 768, zC,
        nullptr, nullptr, 0, xv, wih0c[1], F(26), gxV, 4, 0, nullptr, nullptr);
    gru_rec<<<16*NCHUNK, 512, 0, stream>>>(gxH, gxV, qw0[0], qw0[1], dq0[0], dq0[1], F(19), F(27), y0H, y0V);
    gemm_bt<<<dim3(72,6,8), 256, 0, stream>>>(y0H, wih1c[0], F(22), gxH, 256, 768, zA1, zB1, 768, zC,
        nullptr, nullptr, 0, y0V, wih1c[1], F(30), gxV, 4, 0, nullptr, nullptr);
    gru_rec<<<16*NCHUNK, 512, 0, stream>>>(gxH, gxV, qw1[0], qw1[1], dq1[0], dq1[1], F(23), F(31), z1H, z1V);

    // ---- Stage B ---- (repack_B fused into the GEMM via A-row gather +
    // dup'd/halved weights: K=256, direction-mean folded into the MFMA)
    gemm_bt<<<dim3(72,6,8), 256, 0, stream>>>(z1H, wih0c[2], F(34), gxH, 256, 768, 0, 768LL*256, 768, zC,
        nullptr, nullptr, 0, z1H, wih0c[3], F(42), gxV, 4, 1, z1V, z1H);
    gru_rec<<<16*NCHUNK, 512, 0, stream>>>(gxH, gxV, qw0[2], qw0[3], dq0[2], dq0[3], F(35), F(43), y0H, y0V);
    gemm_bt<<<dim3(72,6,8), 256, 0, stream>>>(y0H, wih1c[2], F(38), gxH, 256, 768, zA1, zB1, 768, zC,
        nullptr, nullptr, 0, y0V, wih1c[3], F(46), gxV, 4, 0, nullptr, nullptr);
    gru_rec<<<16*NCHUNK, 512, 0, stream>>>(gxH, gxV, qw1[2], qw1[3], dq1[2], dq1[3], F(39), F(47), z1H, z1V);

    // ---- combine ---- (repack_comb fused: K=512 gather from z1H/z1V)
    gemm_bt<<<dim3(288,1,1), 256, 0, stream>>>(z1H, wcr, F(12), p3, 512, 128,
        0,0,0,0, F(13), stats + 128, 9216, nullptr, nullptr, nullptr, nullptr, 0,
        2, z1H, z1V);
    final_kernel<<<384, 256, 0, stream>>>(p3, stats + 128, F(14), F(15), (float*)d_out);
}